// Round 7
// baseline (242.740 us; speedup 1.0000x reference)
//
#include <hip/hip_runtime.h>
#include <hip/hip_cooperative_groups.h>
#include <math.h>

namespace cg = cooperative_groups;

// Problem constants (Occ3D-nuScenes volume)
constexpr int   GX = 200, GY = 200, GZ = 16;
constexpr int   TOTAL = GX * GY * GZ;        // 640000 voxels
constexpr int   ND = 16;                     // feature dims
constexpr int   KW = 6;                      // reference window: start + [0,6)
constexpr float VS = 0.4f;
constexpr float VMINX = -40.0f, VMINY = -40.0f, VMINZ = -1.0f;

// Tiling: one WAVE owns a 4x4 x-y patch x full z column (4 z-quads of 4).
// Gaussian z-extent always fits the column -> binning is 2-D (x,y only).
constexpr int   TS = 4;
constexpr int   TX = 50, TY = 50;            // 200/4 x 200/4 patches
constexpr int   NP = TX * TY;                // 2500 patches (one list each)
constexpr int   REC = 32;                    // floats per packed gaussian record (128 B)
constexpr int   CAP = 128;                   // per-patch capacity (lambda~43, max<<128)
constexpr int   BR  = 8;                     // records per staged batch (8*128B = 64*16B)
constexpr int   GRID = 512;                  // cooperative grid: 2 blocks/CU, co-resident
constexpr float NHL2E = -0.72134752044448170f; // -0.5*log2(e): exp(-0.5*m) -> exp2(q)

// Record layout (floats):
//  [0..3]  mx, my, mz, opacity
//  [4..7]  q00, q01*2, q02*2, q11      (inverse cov pre-scaled by NHL2E)
//  [8..11] q12*2, q22, s_packed, e_packed   (bbox packed 8b/axis)
//  [12..15] spare
//  [16..31] features
// d_out layout: [density: TOTAL floats][feats: TOTAL*ND floats]
// d_ws layout:  [gdata: n*REC floats][counts: NP][entries: NP*CAP][cursor: 1]

// Single cooperative kernel: zero -> grid.sync -> prep -> grid.sync -> tile.
// Fusing removes 3 dispatch boundaries (~5-10us each); phase 3 uses per-wave
// dynamic patch assignment (atomic cursor) to fix R6's static load imbalance.
__global__ __launch_bounds__(256) void gv_fused(
    const float* __restrict__ means, const float* __restrict__ covs,
    const float* __restrict__ opac,  const float* __restrict__ feats,
    float* __restrict__ gdata, int* __restrict__ counts,
    int* __restrict__ entries, int* __restrict__ cursor,
    float* __restrict__ out, int n)
{
    cg::grid_group grid = cg::this_grid();
    const int tid = blockIdx.x * 256 + threadIdx.x;
    const int nth = GRID * 256;

    // ---- Phase 1: zero bin counts + work cursor ----
    for (int i = tid; i < NP; i += nth) counts[i] = 0;
    if (tid == 0) *cursor = 0;
    grid.sync();

    // ---- Phase 2: per-gaussian precompute + 2-D binning (grid-stride) ----
    for (int g = tid; g < n; g += nth) {
        const float* cv = covs + (size_t)g * 9;
        // symmetric 3x3: [[a,b,c],[b,d,e],[c,e,f]]
        float a = cv[0], b = cv[1], c = cv[2], d = cv[4], e = cv[5], f = cv[8];
        float A = d * f - e * e;
        float B = c * e - b * f;
        float C = b * e - c * d;
        float invdet = 1.0f / (a * A + b * B + c * C);
        float mx = means[g * 3 + 0], my = means[g * 3 + 1], mz = means[g * 3 + 2];
        float rx = 3.0f * sqrtf(a), ry = 3.0f * sqrtf(d), rz = 3.0f * sqrtf(f);
        // trunc-toward-zero matches .astype(int32)
        int sx = max(0, (int)((mx - rx - VMINX) / VS));
        int sy = max(0, (int)((my - ry - VMINY) / VS));
        int sz = max(0, (int)((mz - rz - VMINZ) / VS));
        // reference window is start + [0,KW) masked by end -> clamp end to start+KW
        int ex = min(GX, (int)((mx + rx - VMINX) / VS) + 1); ex = min(ex, sx + KW);
        int ey = min(GY, (int)((my + ry - VMINY) / VS) + 1); ey = min(ey, sy + KW);
        int ez = min(GZ, (int)((mz + rz - VMINZ) / VS) + 1); ez = min(ez, sz + KW);

        float rec[REC];
        rec[0] = mx; rec[1] = my; rec[2] = mz; rec[3] = opac[g];
        rec[4] = (A * invdet) * NHL2E;                        // q00
        rec[5] = (B * invdet) * (2.0f * NHL2E);               // q01 (doubled)
        rec[6] = (C * invdet) * (2.0f * NHL2E);               // q02 (doubled)
        rec[7] = ((a * f - c * c) * invdet) * NHL2E;          // q11
        rec[8] = ((b * c - a * e) * invdet) * (2.0f * NHL2E); // q12 (doubled)
        rec[9] = ((a * d - b * b) * invdet) * NHL2E;          // q22
        rec[10] = __int_as_float(sx | (sy << 8) | (sz << 16));
        rec[11] = __int_as_float(ex | (ey << 8) | (ez << 16));
        rec[12] = 0.0f; rec[13] = 0.0f; rec[14] = 0.0f; rec[15] = 0.0f;
        const float4* f4 = (const float4*)(feats + (size_t)g * ND);
#pragma unroll
        for (int q = 0; q < 4; ++q) {
            float4 v = f4[q];
            rec[16 + q * 4 + 0] = v.x; rec[16 + q * 4 + 1] = v.y;
            rec[16 + q * 4 + 2] = v.z; rec[16 + q * 4 + 3] = v.w;
        }
        float4* dst = (float4*)(gdata + (size_t)g * REC);   // 128B-aligned
#pragma unroll
        for (int q = 0; q < 8; ++q) dst[q] = ((const float4*)rec)[q];

        // 2-D binning only (z always inside the column)
        int tx0 = sx >> 2, tx1 = (ex - 1) >> 2;
        int ty0 = sy >> 2, ty1 = (ey - 1) >> 2;
        for (int tx = tx0; tx <= tx1; ++tx)
            for (int ty = ty0; ty <= ty1; ++ty) {
                int tile = tx * TY + ty;
                int slot = atomicAdd(&counts[tile], 1);
                if (slot < CAP) entries[(size_t)tile * CAP + slot] = g;
            }
    }
    grid.sync();

    // ---- Phase 3: gather per patch; dynamic per-wave work-stealing ----
    const int wv   = threadIdx.x >> 6;
    const int lane = threadIdx.x & 63;

    __shared__ float sbuf[4][2][BR * REC];   // 4 waves x double buffer x 1 KB

    const int lz2 = lane & 3, ly = (lane >> 2) & 3, lx = lane >> 4;
    float pzcv[4];
    int   izv[4];
#pragma unroll
    for (int v = 0; v < 4; ++v) {
        izv[v] = v * 4 + lz2;
        pzcv[v] = (float)izv[v] * VS + VMINZ;
    }
    const int rlane = lane >> 3;               // record slot within batch (0..7)
    const int flane = lane & 7;                // 16B chunk within record (0..7)
    const int wslot = rlane * REC + flane * 4; // float offset of this lane's chunk

    while (true) {
        int p = 0;
        if (lane == 0) p = atomicAdd(cursor, 1);
        p = __shfl(p, 0, 64);                  // wave-uniform patch id
        if (p >= NP) break;
        const int pty = p % TY;
        const int ptx = p / TY;
        const int ix = ptx * TS + lx, iy = pty * TS + ly;
        const float pxc = (float)ix * VS + VMINX;   // voxel CORNER coords
        const float pyc = (float)iy * VS + VMINY;

        float accd[4];
        float accf[4][ND];
#pragma unroll
        for (int v = 0; v < 4; ++v) {
            accd[v] = 0.0f;
#pragma unroll
            for (int c = 0; c < ND; ++c) accf[v][c] = 0.0f;
            accf[v][ND - 1] = 1e-5f;            // reference: grid_feats[:, -1] = 1e-5
        }

        const int cnt = __builtin_amdgcn_readfirstlane(min(counts[p], CAP));
        const int* __restrict__ el = entries + (size_t)p * CAP;

        if (cnt > 0) {
            const int nb = (cnt + BR - 1) >> 3;
            float* b0 = &sbuf[wv][0][0];
            float* b1 = &sbuf[wv][1][0];

            // Prologue: stage batch 0; prefetch batch 1 data + batch 2 ids.
            int id0 = el[min(rlane, cnt - 1)];
            float4 v0 = *(const float4*)(gdata + (size_t)id0 * REC + flane * 4);
            *(float4*)(b0 + wslot) = v0;
            int idn = el[min(BR + rlane, cnt - 1)];
            float4 vn = *(const float4*)(gdata + (size_t)idn * REC + flane * 4);
            int idn2 = el[min(2 * BR + rlane, cnt - 1)];

            for (int b = 0; b < nb; ++b) {
                if (b + 1 < nb) {
                    float* dstb = ((b + 1) & 1) ? b1 : b0;
                    *(float4*)(dstb + wslot) = vn;            // stage batch b+1
                    vn = *(const float4*)(gdata + (size_t)idn2 * REC + flane * 4);
                    idn2 = el[min((b + 3) * BR + rlane, cnt - 1)];
                }
                const float* rb = (b & 1) ? b1 : b0;
                const int rn = min(BR, cnt - b * BR);
                for (int r = 0; r < rn; ++r) {
                    const float* rec = rb + r * REC;          // wave-uniform -> broadcast
                    float4 q2 = *(const float4*)(rec + 8);    // q12*2, q22, s_pk, e_pk
                    int spk = __float_as_int(q2.z), epk = __float_as_int(q2.w);
                    int sx = spk & 255, sy = (spk >> 8) & 255, sz = (spk >> 16) & 255;
                    int ex = epk & 255, ey = (epk >> 8) & 255, ez = (epk >> 16) & 255;
                    bool in_xy = (ix >= sx) & (ix < ex) & (iy >= sy) & (iy < ey);

                    float4 m  = *(const float4*)(rec);        // mx,my,mz,op
                    float4 q0 = *(const float4*)(rec + 4);    // q00,q01*2,q02*2,q11
                    float px = pxc - m.x;
                    float py = pyc - m.y;
                    // x-y part, computed once per entry:
                    float a1 = fmaf(q0.y, py, q0.x * px);
                    float A0 = fmaf(q0.w * py, py, a1 * px);  // q00x^2+q11y^2+q01'xy
                    float B0 = fmaf(q2.x, py, q0.z * px);     // q02'x + q12'y

                    float4 f0 = *(const float4*)(rec + 16);
                    float4 f1 = *(const float4*)(rec + 20);
                    float4 f2 = *(const float4*)(rec + 24);
                    float4 f3 = *(const float4*)(rec + 28);

                    const int qlo = sz >> 2, qhi = (ez - 1) >> 2;
#pragma unroll
                    for (int v = 0; v < 4; ++v) {
                        if (v < qlo || v > qhi) continue;     // uniform -> execz skip
                        float pz = pzcv[v] - m.z;
                        float q = fmaf(pz, fmaf(q2.y, pz, B0), A0);
                        float dens = m.w * __builtin_amdgcn_exp2f(q);
                        bool in = in_xy & (izv[v] >= sz) & (izv[v] < ez);
                        dens = in ? dens : 0.0f;
                        accd[v] += dens;
                        accf[v][0]  = fmaf(dens, f0.x, accf[v][0]);
                        accf[v][1]  = fmaf(dens, f0.y, accf[v][1]);
                        accf[v][2]  = fmaf(dens, f0.z, accf[v][2]);
                        accf[v][3]  = fmaf(dens, f0.w, accf[v][3]);
                        accf[v][4]  = fmaf(dens, f1.x, accf[v][4]);
                        accf[v][5]  = fmaf(dens, f1.y, accf[v][5]);
                        accf[v][6]  = fmaf(dens, f1.z, accf[v][6]);
                        accf[v][7]  = fmaf(dens, f1.w, accf[v][7]);
                        accf[v][8]  = fmaf(dens, f2.x, accf[v][8]);
                        accf[v][9]  = fmaf(dens, f2.y, accf[v][9]);
                        accf[v][10] = fmaf(dens, f2.z, accf[v][10]);
                        accf[v][11] = fmaf(dens, f2.w, accf[v][11]);
                        accf[v][12] = fmaf(dens, f3.x, accf[v][12]);
                        accf[v][13] = fmaf(dens, f3.y, accf[v][13]);
                        accf[v][14] = fmaf(dens, f3.z, accf[v][14]);
                        accf[v][15] = fmaf(dens, f3.w, accf[v][15]);
                    }
                }
            }
        }

        // Epilogue: density (raw) + normalized features; each voxel exactly once.
#pragma unroll
        for (int v = 0; v < 4; ++v) {
            const int flat = (ix * GY + iy) * GZ + izv[v];
            out[flat] = accd[v];
            float inv = 1.0f / fmaxf(accd[v], 1e-6f);   // clip(density, 1e-6, None)
            float4* fo = (float4*)(out + TOTAL + (size_t)flat * ND);
#pragma unroll
            for (int q = 0; q < 4; ++q) {
                float4 w;
                w.x = accf[v][q * 4 + 0] * inv;
                w.y = accf[v][q * 4 + 1] * inv;
                w.z = accf[v][q * 4 + 2] * inv;
                w.w = accf[v][q * 4 + 3] * inv;
                fo[q] = w;
            }
        }
    }
}

extern "C" void kernel_launch(void* const* d_in, const int* in_sizes, int n_in,
                              void* d_out, int out_size, void* d_ws, size_t ws_size,
                              hipStream_t stream) {
    const float* means = (const float*)d_in[0];   // [N,3]
    const float* covs  = (const float*)d_in[1];   // [N,3,3]
    const float* opac  = (const float*)d_in[2];   // [N]
    const float* feats = (const float*)d_in[3];   // [N,16]
    float* out = (float*)d_out;                   // [TOTAL + TOTAL*ND]
    int n = in_sizes[2];

    float* gdata   = (float*)d_ws;                            // n*REC floats (4 MB)
    int*   counts  = (int*)(gdata + (size_t)n * REC);         // NP ints
    int*   entries = counts + ((NP + 63) & ~63);              // NP*CAP ints (1.28 MB)
    int*   cursor  = entries + (size_t)NP * CAP;              // 1 int

    void* args[] = {(void*)&means, (void*)&covs, (void*)&opac, (void*)&feats,
                    (void*)&gdata, (void*)&counts, (void*)&entries, (void*)&cursor,
                    (void*)&out, (void*)&n};
    hipLaunchCooperativeKernel((const void*)gv_fused, dim3(GRID), dim3(256),
                               args, 0, stream);
}

// Round 8
// 147.445 us; speedup vs baseline: 1.6463x; 1.6463x over previous
//
#include <hip/hip_runtime.h>
#include <math.h>

// Problem constants (Occ3D-nuScenes volume)
constexpr int   GX = 200, GY = 200, GZ = 16;
constexpr int   TOTAL = GX * GY * GZ;        // 640000 voxels
constexpr int   ND = 16;                     // feature dims
constexpr int   KW = 6;                      // reference window: start + [0,6)
constexpr float VS = 0.4f;
constexpr float VMINX = -40.0f, VMINY = -40.0f, VMINZ = -1.0f;

// Tiling: one WAVE owns a 4x4 x-y patch x full z column (4 z-quads of 4).
// Gaussian z-extent always fits the column -> binning is 2-D (x,y only).
constexpr int   TS = 4;
constexpr int   TX = 50, TY = 50;            // 200/4 x 200/4 patches
constexpr int   NP = TX * TY;                // 2500 patches (one list each)
constexpr int   REC = 32;                    // floats per packed gaussian record (128 B)
constexpr int   CAP = 128;                   // per-patch capacity (lambda~50, max~90)
constexpr int   BR  = 8;                     // records per staged batch (8*128B = 64*16B)
constexpr int   GRIDB = 512;                 // tile kernel blocks (2/CU, 2048 worker waves)
constexpr float NHL2E = -0.72134752044448170f; // -0.5*log2(e): exp(-0.5*m) -> exp2(q)

// Record layout (floats):
//  [0..3]  mx, my, mz, opacity
//  [4..7]  q00, q01*2, q02*2, q11      (inverse cov pre-scaled by NHL2E)
//  [8..11] q12*2, q22, s_packed, e_packed   (bbox packed 8b/axis)
//  [12..15] spare
//  [16..31] features
// d_out layout: [density: TOTAL floats][feats: TOTAL*ND floats]
// d_ws layout:  [gdata: n*REC floats][counts: NP][cursor: 1][entries: NP*CAP]

__global__ __launch_bounds__(256) void gv_prep(
    const float* __restrict__ means, const float* __restrict__ covs,
    const float* __restrict__ opac,  const float* __restrict__ feats,
    float* __restrict__ gdata, int* __restrict__ counts,
    int* __restrict__ entries, int n)
{
    int g = blockIdx.x * 256 + threadIdx.x;
    if (g >= n) return;
    const float* cv = covs + (size_t)g * 9;
    // symmetric 3x3: [[a,b,c],[b,d,e],[c,e,f]]
    float a = cv[0], b = cv[1], c = cv[2], d = cv[4], e = cv[5], f = cv[8];
    float A = d * f - e * e;
    float B = c * e - b * f;
    float C = b * e - c * d;
    float invdet = 1.0f / (a * A + b * B + c * C);
    float mx = means[g * 3 + 0], my = means[g * 3 + 1], mz = means[g * 3 + 2];
    float rx = 3.0f * sqrtf(a), ry = 3.0f * sqrtf(d), rz = 3.0f * sqrtf(f);
    // trunc-toward-zero matches .astype(int32)
    int sx = max(0, (int)((mx - rx - VMINX) / VS));
    int sy = max(0, (int)((my - ry - VMINY) / VS));
    int sz = max(0, (int)((mz - rz - VMINZ) / VS));
    // reference window is start + [0,KW) masked by end -> clamp end to start+KW
    int ex = min(GX, (int)((mx + rx - VMINX) / VS) + 1); ex = min(ex, sx + KW);
    int ey = min(GY, (int)((my + ry - VMINY) / VS) + 1); ey = min(ey, sy + KW);
    int ez = min(GZ, (int)((mz + rz - VMINZ) / VS) + 1); ez = min(ez, sz + KW);

    float rec[REC];
    rec[0] = mx; rec[1] = my; rec[2] = mz; rec[3] = opac[g];
    rec[4] = (A * invdet) * NHL2E;                        // q00
    rec[5] = (B * invdet) * (2.0f * NHL2E);               // q01 (doubled)
    rec[6] = (C * invdet) * (2.0f * NHL2E);               // q02 (doubled)
    rec[7] = ((a * f - c * c) * invdet) * NHL2E;          // q11
    rec[8] = ((b * c - a * e) * invdet) * (2.0f * NHL2E); // q12 (doubled)
    rec[9] = ((a * d - b * b) * invdet) * NHL2E;          // q22
    rec[10] = __int_as_float(sx | (sy << 8) | (sz << 16));
    rec[11] = __int_as_float(ex | (ey << 8) | (ez << 16));
    rec[12] = 0.0f; rec[13] = 0.0f; rec[14] = 0.0f; rec[15] = 0.0f;
    const float4* f4 = (const float4*)(feats + (size_t)g * ND);
#pragma unroll
    for (int q = 0; q < 4; ++q) {
        float4 v = f4[q];
        rec[16 + q * 4 + 0] = v.x; rec[16 + q * 4 + 1] = v.y;
        rec[16 + q * 4 + 2] = v.z; rec[16 + q * 4 + 3] = v.w;
    }
    float4* dst = (float4*)(gdata + (size_t)g * REC);   // 128B-aligned
#pragma unroll
    for (int q = 0; q < 8; ++q) dst[q] = ((const float4*)rec)[q];

    // 2-D binning only (z always inside the column)
    int tx0 = sx >> 2, tx1 = (ex - 1) >> 2;
    int ty0 = sy >> 2, ty1 = (ey - 1) >> 2;
    for (int tx = tx0; tx <= tx1; ++tx)
        for (int ty = ty0; ty <= ty1; ++ty) {
            int tile = tx * TY + ty;
            int slot = atomicAdd(&counts[tile], 1);
            if (slot < CAP) entries[(size_t)tile * CAP + slot] = g;
        }
}

// One WAVE per 4x4 x-y patch x full z column (68 accumulators/lane). R7's
// post-mortem: __launch_bounds__(256) let the compiler cap VGPRs at 64 ->
// the 68-reg accumulator array spilled to scratch in the hot loop (R6/R7
// regression). (256,2) raises the cap to 128 (2 blocks/CU resident).
// Patches are pulled by wave-level work stealing (atomic cursor) to fix the
// static-assignment imbalance. Records staged to LDS in 8-record batches,
// double-buffered; reads are wave-uniform broadcasts. Each voxel written
// exactly once with normalization fused -> no global atomics.
__global__ __launch_bounds__(256, 2) void gv_tile(
    const float* __restrict__ gdata, const int* __restrict__ counts,
    const int* __restrict__ entries, int* __restrict__ cursor,
    float* __restrict__ out)
{
    const int wv   = threadIdx.x >> 6;
    const int lane = threadIdx.x & 63;

    __shared__ float sbuf[4][2][BR * REC];   // 4 waves x double buffer x 1 KB

    const int lz2 = lane & 3, ly = (lane >> 2) & 3, lx = lane >> 4;
    float pzcv[4];
    int   izv[4];
#pragma unroll
    for (int v = 0; v < 4; ++v) {
        izv[v] = v * 4 + lz2;
        pzcv[v] = (float)izv[v] * VS + VMINZ;
    }
    const int rlane = lane >> 3;               // record slot within batch (0..7)
    const int flane = lane & 7;                // 16B chunk within record (0..7)
    const int wslot = rlane * REC + flane * 4; // float offset of this lane's chunk

    while (true) {
        int p = 0;
        if (lane == 0) p = atomicAdd(cursor, 1);
        p = __builtin_amdgcn_readfirstlane(__shfl(p, 0, 64));  // wave-uniform patch id
        if (p >= NP) break;
        const int pty = p % TY;
        const int ptx = p / TY;
        const int ix = ptx * TS + lx, iy = pty * TS + ly;
        const float pxc = (float)ix * VS + VMINX;   // voxel CORNER coords
        const float pyc = (float)iy * VS + VMINY;

        float accd[4];
        float accf[4][ND];
#pragma unroll
        for (int v = 0; v < 4; ++v) {
            accd[v] = 0.0f;
#pragma unroll
            for (int c = 0; c < ND; ++c) accf[v][c] = 0.0f;
            accf[v][ND - 1] = 1e-5f;            // reference: grid_feats[:, -1] = 1e-5
        }

        const int cnt = __builtin_amdgcn_readfirstlane(min(counts[p], CAP));
        const int* __restrict__ el = entries + (size_t)p * CAP;

        if (cnt > 0) {
            const int nb = (cnt + BR - 1) >> 3;
            float* b0 = &sbuf[wv][0][0];
            float* b1 = &sbuf[wv][1][0];

            // Prologue: stage batch 0; prefetch batch 1 data + batch 2 ids.
            int id0 = el[min(rlane, cnt - 1)];
            float4 v0 = *(const float4*)(gdata + (size_t)id0 * REC + flane * 4);
            *(float4*)(b0 + wslot) = v0;
            int idn = el[min(BR + rlane, cnt - 1)];
            float4 vn = *(const float4*)(gdata + (size_t)idn * REC + flane * 4);
            int idn2 = el[min(2 * BR + rlane, cnt - 1)];

            for (int b = 0; b < nb; ++b) {
                if (b + 1 < nb) {
                    float* dstb = ((b + 1) & 1) ? b1 : b0;
                    *(float4*)(dstb + wslot) = vn;            // stage batch b+1
                    vn = *(const float4*)(gdata + (size_t)idn2 * REC + flane * 4);
                    idn2 = el[min((b + 3) * BR + rlane, cnt - 1)];
                }
                const float* rb = (b & 1) ? b1 : b0;
                const int rn = min(BR, cnt - b * BR);
                for (int r = 0; r < rn; ++r) {
                    const float* rec = rb + r * REC;          // wave-uniform -> broadcast
                    float4 q2 = *(const float4*)(rec + 8);    // q12*2, q22, s_pk, e_pk
                    int spk = __float_as_int(q2.z), epk = __float_as_int(q2.w);
                    int sx = spk & 255, sy = (spk >> 8) & 255, sz = (spk >> 16) & 255;
                    int ex = epk & 255, ey = (epk >> 8) & 255, ez = (epk >> 16) & 255;
                    bool in_xy = (ix >= sx) & (ix < ex) & (iy >= sy) & (iy < ey);

                    float4 m  = *(const float4*)(rec);        // mx,my,mz,op
                    float4 q0 = *(const float4*)(rec + 4);    // q00,q01*2,q02*2,q11
                    float px = pxc - m.x;
                    float py = pyc - m.y;
                    // x-y part, computed once per entry:
                    float a1 = fmaf(q0.y, py, q0.x * px);
                    float A0 = fmaf(q0.w * py, py, a1 * px);  // q00x^2+q11y^2+q01'xy
                    float B0 = fmaf(q2.x, py, q0.z * px);     // q02'x + q12'y

                    float4 f0 = *(const float4*)(rec + 16);
                    float4 f1 = *(const float4*)(rec + 20);
                    float4 f2 = *(const float4*)(rec + 24);
                    float4 f3 = *(const float4*)(rec + 28);

                    // wave-uniform z-quad range -> scalar branches skip dead quads
                    const int qlo = __builtin_amdgcn_readfirstlane(sz) >> 2;
                    const int qhi = (__builtin_amdgcn_readfirstlane(ez) - 1) >> 2;
#pragma unroll
                    for (int v = 0; v < 4; ++v) {
                        if (v < qlo || v > qhi) continue;
                        float pz = pzcv[v] - m.z;
                        float q = fmaf(pz, fmaf(q2.y, pz, B0), A0);
                        float dens = m.w * __builtin_amdgcn_exp2f(q);
                        bool in = in_xy & (izv[v] >= sz) & (izv[v] < ez);
                        dens = in ? dens : 0.0f;
                        accd[v] += dens;
                        accf[v][0]  = fmaf(dens, f0.x, accf[v][0]);
                        accf[v][1]  = fmaf(dens, f0.y, accf[v][1]);
                        accf[v][2]  = fmaf(dens, f0.z, accf[v][2]);
                        accf[v][3]  = fmaf(dens, f0.w, accf[v][3]);
                        accf[v][4]  = fmaf(dens, f1.x, accf[v][4]);
                        accf[v][5]  = fmaf(dens, f1.y, accf[v][5]);
                        accf[v][6]  = fmaf(dens, f1.z, accf[v][6]);
                        accf[v][7]  = fmaf(dens, f1.w, accf[v][7]);
                        accf[v][8]  = fmaf(dens, f2.x, accf[v][8]);
                        accf[v][9]  = fmaf(dens, f2.y, accf[v][9]);
                        accf[v][10] = fmaf(dens, f2.z, accf[v][10]);
                        accf[v][11] = fmaf(dens, f2.w, accf[v][11]);
                        accf[v][12] = fmaf(dens, f3.x, accf[v][12]);
                        accf[v][13] = fmaf(dens, f3.y, accf[v][13]);
                        accf[v][14] = fmaf(dens, f3.z, accf[v][14]);
                        accf[v][15] = fmaf(dens, f3.w, accf[v][15]);
                    }
                }
            }
        }

        // Epilogue: density (raw) + normalized features; each voxel exactly once.
#pragma unroll
        for (int v = 0; v < 4; ++v) {
            const int flat = (ix * GY + iy) * GZ + izv[v];
            out[flat] = accd[v];
            float inv = 1.0f / fmaxf(accd[v], 1e-6f);   // clip(density, 1e-6, None)
            float4* fo = (float4*)(out + TOTAL + (size_t)flat * ND);
#pragma unroll
            for (int q = 0; q < 4; ++q) {
                float4 w;
                w.x = accf[v][q * 4 + 0] * inv;
                w.y = accf[v][q * 4 + 1] * inv;
                w.z = accf[v][q * 4 + 2] * inv;
                w.w = accf[v][q * 4 + 3] * inv;
                fo[q] = w;
            }
        }
    }
}

extern "C" void kernel_launch(void* const* d_in, const int* in_sizes, int n_in,
                              void* d_out, int out_size, void* d_ws, size_t ws_size,
                              hipStream_t stream) {
    const float* means = (const float*)d_in[0];   // [N,3]
    const float* covs  = (const float*)d_in[1];   // [N,3,3]
    const float* opac  = (const float*)d_in[2];   // [N]
    const float* feats = (const float*)d_in[3];   // [N,16]
    float* out = (float*)d_out;                   // [TOTAL + TOTAL*ND]
    const int n = in_sizes[2];

    float* gdata   = (float*)d_ws;                            // n*REC floats (4 MB)
    int*   counts  = (int*)(gdata + (size_t)n * REC);         // NP ints
    int*   cursor  = counts + NP;                             // 1 int (memset with counts)
    int*   entries = counts + ((NP + 1 + 63) & ~63);          // NP*CAP ints (1.28 MB)

    hipMemsetAsync(counts, 0, (NP + 1) * sizeof(int), stream);
    gv_prep<<<(n + 255) / 256, 256, 0, stream>>>(means, covs, opac, feats,
                                                 gdata, counts, entries, n);
    gv_tile<<<GRIDB, 256, 0, stream>>>(gdata, counts, entries, cursor, out);
}

// Round 9
// 106.368 us; speedup vs baseline: 2.2821x; 1.3862x over previous
//
#include <hip/hip_runtime.h>
#include <math.h>

// Problem constants (Occ3D-nuScenes volume)
constexpr int   GX = 200, GY = 200, GZ = 16;
constexpr int   TOTAL = GX * GY * GZ;        // 640000 voxels
constexpr int   ND = 16;                     // feature dims
constexpr int   KW = 6;                      // reference window: start + [0,6)
constexpr float VS = 0.4f;
constexpr float VMINX = -40.0f, VMINY = -40.0f, VMINZ = -1.0f;

// Tiling: 4x4x4 voxel tiles; one WAVE per tile (1 voxel/lane, 17 accumulators
// -> ~40 VGPR, no pressure). Proven R4/R5 shape; R6-R8's 68-accumulator
// z-column variants all lost to register-allocation pathologies.
constexpr int   TS = 4;
constexpr int   TX = 50, TY = 50, TZ = 4;    // 200/4, 200/4, 16/4
constexpr int   NT = TX * TY * TZ;           // 10000 tiles
constexpr int   RS = 20;                     // floats per record (80 B, was 128 B)
constexpr int   CAP = 128;                   // per-tile capacity (lambda~13, max~55)
constexpr int   BR  = 12;                    // records per staged batch (12*80B = 60*16B)
constexpr float NHL2E = -0.72134752044448170f; // -0.5*log2(e): exp(-0.5*m) -> exp2(q)

// Record layout (floats), 80 B -> 5 LDS reads/entry instead of 7 (LDS broadcast
// pipe is the measured bottleneck):
//  [0..3]   mx, my, mz, opacity
//  [4..7]   q00, q01*2, q02*2, q11    (inverse cov pre-scaled by NHL2E)
//  [8..11]  q12*2, q22, s_packed, e_packed  (bbox packed 8b/axis)
//  [12..19] features as bf16 (RNE), 2 per uint
// d_out layout: [density: TOTAL floats][feats: TOTAL*ND floats]
// d_ws layout:  [gdata: n*RS floats][counts: NT][entries: NT*CAP]

__device__ __forceinline__ unsigned bf16_rne(float x) {
    unsigned u = __float_as_uint(x);
    return (u + 0x7fffu + ((u >> 16) & 1u)) >> 16;
}

__global__ __launch_bounds__(256) void gv_prep(
    const float* __restrict__ means, const float* __restrict__ covs,
    const float* __restrict__ opac,  const float* __restrict__ feats,
    float* __restrict__ gdata, int* __restrict__ counts,
    int* __restrict__ entries, int n)
{
    int g = blockIdx.x * 256 + threadIdx.x;
    if (g >= n) return;
    const float* cv = covs + (size_t)g * 9;
    // symmetric 3x3: [[a,b,c],[b,d,e],[c,e,f]]
    float a = cv[0], b = cv[1], c = cv[2], d = cv[4], e = cv[5], f = cv[8];
    float A = d * f - e * e;
    float B = c * e - b * f;
    float C = b * e - c * d;
    float invdet = 1.0f / (a * A + b * B + c * C);
    float mx = means[g * 3 + 0], my = means[g * 3 + 1], mz = means[g * 3 + 2];
    float rx = 3.0f * sqrtf(a), ry = 3.0f * sqrtf(d), rz = 3.0f * sqrtf(f);
    // trunc-toward-zero matches .astype(int32)
    int sx = max(0, (int)((mx - rx - VMINX) / VS));
    int sy = max(0, (int)((my - ry - VMINY) / VS));
    int sz = max(0, (int)((mz - rz - VMINZ) / VS));
    // reference window is start + [0,KW) masked by end -> clamp end to start+KW
    int ex = min(GX, (int)((mx + rx - VMINX) / VS) + 1); ex = min(ex, sx + KW);
    int ey = min(GY, (int)((my + ry - VMINY) / VS) + 1); ey = min(ey, sy + KW);
    int ez = min(GZ, (int)((mz + rz - VMINZ) / VS) + 1); ez = min(ez, sz + KW);

    float rec[RS];
    rec[0] = mx; rec[1] = my; rec[2] = mz; rec[3] = opac[g];
    rec[4] = (A * invdet) * NHL2E;                        // q00
    rec[5] = (B * invdet) * (2.0f * NHL2E);               // q01 (doubled)
    rec[6] = (C * invdet) * (2.0f * NHL2E);               // q02 (doubled)
    rec[7] = ((a * f - c * c) * invdet) * NHL2E;          // q11
    rec[8] = ((b * c - a * e) * invdet) * (2.0f * NHL2E); // q12 (doubled)
    rec[9] = ((a * d - b * b) * invdet) * NHL2E;          // q22
    rec[10] = __int_as_float(sx | (sy << 8) | (sz << 16));
    rec[11] = __int_as_float(ex | (ey << 8) | (ez << 16));
    const float* fr = feats + (size_t)g * ND;
#pragma unroll
    for (int q = 0; q < 8; ++q) {
        unsigned lo = bf16_rne(fr[2 * q]);
        unsigned hi = bf16_rne(fr[2 * q + 1]);
        rec[12 + q] = __uint_as_float(lo | (hi << 16));
    }
    float4* dst = (float4*)(gdata + (size_t)g * RS);   // 80B stride, 16B aligned
#pragma unroll
    for (int q = 0; q < 5; ++q) dst[q] = ((const float4*)rec)[q];

    // 3-D binning at 4^3
    int tx0 = sx >> 2, tx1 = (ex - 1) >> 2;
    int ty0 = sy >> 2, ty1 = (ey - 1) >> 2;
    int tz0 = sz >> 2, tz1 = (ez - 1) >> 2;
    for (int tx = tx0; tx <= tx1; ++tx)
        for (int ty = ty0; ty <= ty1; ++ty)
            for (int tz = tz0; tz <= tz1; ++tz) {
                int tile = (tx * TY + ty) * TZ + tz;
                int slot = atomicAdd(&counts[tile], 1);
                if (slot < CAP) entries[(size_t)tile * CAP + slot] = g;
            }
}

// One WAVE per 4x4x4 tile; 1 voxel/lane, 17 register accumulators. Records
// staged to LDS in 12-record (960 B) batches: lanes 0..59 each move one 16 B
// chunk (rl=lane/5, fc=lane%5). Double-buffered, global data one batch ahead,
// entry ids two ahead -> in-order vmcnt waits. Compute reads records at
// wave-uniform LDS addresses (pure broadcast). bf16 features halve the
// bottleneck LDS-broadcast bytes. Each voxel written exactly once with
// normalization fused -> no global atomics, no init/norm passes.
__global__ __launch_bounds__(256) void gv_tile(
    const float* __restrict__ gdata, const int* __restrict__ counts,
    const int* __restrict__ entries, float* __restrict__ out)
{
    const int wv   = threadIdx.x >> 6;
    const int lane = threadIdx.x & 63;
    const int p    = blockIdx.x * 4 + wv;    // tile id 0..9999
    const int tz   = p % TZ;
    const int ty   = (p / TZ) % TY;
    const int tx   = p / (TZ * TY);

    __shared__ float sbuf[4][2][BR * RS];    // 4 waves x double buffer x 960 B

    const int lz = lane & 3, ly = (lane >> 2) & 3, lx = lane >> 4;
    const int ix = tx * TS + lx, iy = ty * TS + ly, iz = tz * TS + lz;
    const float pxc = (float)ix * VS + VMINX;   // voxel CORNER coords
    const float pyc = (float)iy * VS + VMINY;
    const float pzc = (float)iz * VS + VMINZ;

    float accd = 0.0f;
    float accf[ND];
#pragma unroll
    for (int c = 0; c < ND; ++c) accf[c] = 0.0f;
    accf[ND - 1] = 1e-5f;                       // reference: grid_feats[:, -1] = 1e-5

    const int cnt = __builtin_amdgcn_readfirstlane(min(counts[p], CAP));
    const int* __restrict__ el = entries + (size_t)p * CAP;

    const int  rl = lane / 5;                  // record slot within batch (0..11)
    const int  fc = lane - rl * 5;             // 16B chunk within record (0..4)
    const bool stager = lane < 60;
    const int  wslot = rl * RS + fc * 4;       // float offset of this lane's chunk

    if (cnt > 0) {
        const int nb = (cnt + BR - 1) / BR;
        float* b0 = &sbuf[wv][0][0];
        float* b1 = &sbuf[wv][1][0];

        // Prologue: stage batch 0; prefetch batch 1 data + batch 2 ids.
        float4 vn; int idn2 = 0;
        if (stager) {
            int id0 = el[min(rl, cnt - 1)];
            float4 v0 = *(const float4*)(gdata + (size_t)id0 * RS + fc * 4);
            *(float4*)(b0 + wslot) = v0;
            int idn = el[min(BR + rl, cnt - 1)];
            vn = *(const float4*)(gdata + (size_t)idn * RS + fc * 4);
            idn2 = el[min(2 * BR + rl, cnt - 1)];
        }

        for (int b = 0; b < nb; ++b) {
            if (b + 1 < nb && stager) {
                float* dstb = ((b + 1) & 1) ? b1 : b0;
                *(float4*)(dstb + wslot) = vn;                // stage batch b+1
                vn = *(const float4*)(gdata + (size_t)idn2 * RS + fc * 4);
                idn2 = el[min((b + 3) * BR + rl, cnt - 1)];
            }
            const float* rb = (b & 1) ? b1 : b0;
            const int rn = min(BR, cnt - b * BR);
            for (int r = 0; r < rn; ++r) {
                const float* rec = rb + r * RS;               // wave-uniform -> broadcast
                float4 c2 = *(const float4*)(rec + 8);        // q12*2, q22, s_pk, e_pk
                int spk = __float_as_int(c2.z), epk = __float_as_int(c2.w);
                int sx = spk & 255, sy = (spk >> 8) & 255, sz = (spk >> 16) & 255;
                int ex = epk & 255, ey = (epk >> 8) & 255, ez = (epk >> 16) & 255;
                bool in = (ix >= sx) & (ix < ex)
                        & (iy >= sy) & (iy < ey)
                        & (iz >= sz) & (iz < ez);

                float4 c0 = *(const float4*)(rec);            // mx,my,mz,op
                float4 c1 = *(const float4*)(rec + 4);        // q00,q01*2,q02*2,q11
                float px = pxc - c0.x;
                float py = pyc - c0.y;
                float pz = pzc - c0.z;
                float q = c1.x * px * px + c1.w * py * py + c2.y * pz * pz
                        + c1.y * px * py + c1.z * px * pz + c2.x * py * pz;
                float dens = c0.w * __builtin_amdgcn_exp2f(q);
                dens = in ? dens : 0.0f;
                accd += dens;

                uint4 fA = *(const uint4*)(rec + 12);         // bf16 feats 0..7
                uint4 fB = *(const uint4*)(rec + 16);         // bf16 feats 8..15
#define BFLO(u) __uint_as_float((u) << 16)
#define BFHI(u) __uint_as_float((u) & 0xffff0000u)
                accf[0]  = fmaf(dens, BFLO(fA.x), accf[0]);
                accf[1]  = fmaf(dens, BFHI(fA.x), accf[1]);
                accf[2]  = fmaf(dens, BFLO(fA.y), accf[2]);
                accf[3]  = fmaf(dens, BFHI(fA.y), accf[3]);
                accf[4]  = fmaf(dens, BFLO(fA.z), accf[4]);
                accf[5]  = fmaf(dens, BFHI(fA.z), accf[5]);
                accf[6]  = fmaf(dens, BFLO(fA.w), accf[6]);
                accf[7]  = fmaf(dens, BFHI(fA.w), accf[7]);
                accf[8]  = fmaf(dens, BFLO(fB.x), accf[8]);
                accf[9]  = fmaf(dens, BFHI(fB.x), accf[9]);
                accf[10] = fmaf(dens, BFLO(fB.y), accf[10]);
                accf[11] = fmaf(dens, BFHI(fB.y), accf[11]);
                accf[12] = fmaf(dens, BFLO(fB.z), accf[12]);
                accf[13] = fmaf(dens, BFHI(fB.z), accf[13]);
                accf[14] = fmaf(dens, BFLO(fB.w), accf[14]);
                accf[15] = fmaf(dens, BFHI(fB.w), accf[15]);
#undef BFLO
#undef BFHI
            }
        }
    }

    // Epilogue: density (raw) + normalized features; each voxel exactly once.
    const int flat = (ix * GY + iy) * GZ + iz;
    out[flat] = accd;
    float inv = 1.0f / fmaxf(accd, 1e-6f);      // clip(density, 1e-6, None)
    float4* fo = (float4*)(out + TOTAL + (size_t)flat * ND);
#pragma unroll
    for (int q = 0; q < 4; ++q) {
        float4 w;
        w.x = accf[q * 4 + 0] * inv;
        w.y = accf[q * 4 + 1] * inv;
        w.z = accf[q * 4 + 2] * inv;
        w.w = accf[q * 4 + 3] * inv;
        fo[q] = w;
    }
}

extern "C" void kernel_launch(void* const* d_in, const int* in_sizes, int n_in,
                              void* d_out, int out_size, void* d_ws, size_t ws_size,
                              hipStream_t stream) {
    const float* means = (const float*)d_in[0];   // [N,3]
    const float* covs  = (const float*)d_in[1];   // [N,3,3]
    const float* opac  = (const float*)d_in[2];   // [N]
    const float* feats = (const float*)d_in[3];   // [N,16]
    float* out = (float*)d_out;                   // [TOTAL + TOTAL*ND]
    const int n = in_sizes[2];

    float* gdata   = (float*)d_ws;                            // n*RS floats (2.6 MB)
    int*   counts  = (int*)(gdata + (size_t)n * RS);          // NT ints
    int*   entries = counts + ((NT + 63) & ~63);              // NT*CAP ints (5.12 MB)

    hipMemsetAsync(counts, 0, NT * sizeof(int), stream);
    gv_prep<<<(n + 255) / 256, 256, 0, stream>>>(means, covs, opac, feats,
                                                 gdata, counts, entries, n);
    gv_tile<<<NT / 4, 256, 0, stream>>>(gdata, counts, entries, out);
}